// Round 6
// baseline (348.082 us; speedup 1.0000x reference)
//
#include <hip/hip_runtime.h>

#define CDIM 2048
#define BATCH 32
#define K2 4096

typedef float f32x4 __attribute__((ext_vector_type(4)));

// ---- GEMM partial: x_partial[kt] = xcat[:, k0:k0+BK] @ W[:, k0:k0+BK]^T ----
#define BN 64
#define BK 128
#define KT (K2 / BK)   // 32
#define NT (CDIM / BN) // 32

__global__ __launch_bounds__(256) void gemm_partial_k(
    const float* __restrict__ x1, const float* __restrict__ x2,
    const float* __restrict__ W, float* __restrict__ partial)
{
    __shared__ float Xs[BATCH][BK + 1];
    __shared__ float Wt[BN][BK + 1];
    const int nt = blockIdx.x, kt = blockIdx.y;
    const int i0 = nt * BN, k0 = kt * BK;
    const int t = threadIdx.x;

    const float* xsrc = (k0 < CDIM) ? x1 : x2;
    const int kk0 = k0 & (CDIM - 1);

    #pragma unroll
    for (int r = 0; r < 4; ++r) {
        int f = t + 256 * r;
        int b = f >> 5, c4 = (f & 31) * 4;
        float4 v = *reinterpret_cast<const float4*>(xsrc + b * CDIM + kk0 + c4);
        Xs[b][c4 + 0] = v.x; Xs[b][c4 + 1] = v.y;
        Xs[b][c4 + 2] = v.z; Xs[b][c4 + 3] = v.w;
    }
    #pragma unroll
    for (int r = 0; r < 8; ++r) {
        int f = t + 256 * r;
        int row = f >> 5, c4 = (f & 31) * 4;
        float4 v = *reinterpret_cast<const float4*>(W + (size_t)(i0 + row) * K2 + k0 + c4);
        Wt[row][c4 + 0] = v.x; Wt[row][c4 + 1] = v.y;
        Wt[row][c4 + 2] = v.z; Wt[row][c4 + 3] = v.w;
    }
    __syncthreads();

    const int j = t & 31, bg = t >> 5;
    const int il = j * 2, b0 = bg * 4;
    float acc[4][2] = {};
    #pragma unroll 4
    for (int kk = 0; kk < BK; ++kk) {
        float w0 = Wt[il][kk], w1 = Wt[il + 1][kk];
        #pragma unroll
        for (int bb = 0; bb < 4; ++bb) {
            float xv = Xs[b0 + bb][kk];
            acc[bb][0] = fmaf(xv, w0, acc[bb][0]);
            acc[bb][1] = fmaf(xv, w1, acc[bb][1]);
        }
    }
    #pragma unroll
    for (int bb = 0; bb < 4; ++bb) {
        float2 v = make_float2(acc[bb][0], acc[bb][1]);
        *reinterpret_cast<float2*>(partial + (size_t)kt * (BATCH * CDIM)
                                   + (b0 + bb) * CDIM + i0 + il) = v;
    }
}

__global__ __launch_bounds__(256) void reduce_x_k(
    const float* __restrict__ partial, const float* __restrict__ bias,
    float* __restrict__ x)
{
    int idx = blockIdx.x * 256 + threadIdx.x;
    float s = 0.f;
    #pragma unroll
    for (int kt = 0; kt < KT; ++kt) s += partial[(size_t)kt * (BATCH * CDIM) + idx];
    x[idx] = s + bias[idx & (CDIM - 1)];
}

// ---- Attention (R5 structure, plus runtime `reps` for DIAGNOSTIC profiling:
// the row loop is re-executed reps times producing identical outputs, so the
// attn dispatch exceeds the harness fill kernels' ~320us and surfaces in the
// rocprof top-5 with its FETCH/WRITE/VALU/occupancy counters.) ----
__global__ __launch_bounds__(256) void attn_k(
    const float* __restrict__ x, const float* __restrict__ x1,
    const float* __restrict__ x2, float* __restrict__ out1,
    float* __restrict__ out2, float* __restrict__ att, int reps)
{
    __shared__ float xs[CDIM];
    __shared__ float xs1[CDIM];
    __shared__ float xs2[CDIM];
    __shared__ float wred[8];
    const int b = blockIdx.x >> 5, rg = blockIdx.x & 31;
    const int t = threadIdx.x;
    const int lane = t & 63, wv = t >> 6;
    const float* xb  = x  + b * CDIM;
    const float* x1b = x1 + b * CDIM;
    const float* x2b = x2 + b * CDIM;

    #pragma unroll
    for (int r = 0; r < 2; ++r) {
        int f = (t + 256 * r) * 4;
        *reinterpret_cast<float4*>(&xs[f])  = *reinterpret_cast<const float4*>(xb  + f);
        *reinterpret_cast<float4*>(&xs1[f]) = *reinterpret_cast<const float4*>(x1b + f);
        *reinterpret_cast<float4*>(&xs2[f]) = *reinterpret_cast<const float4*>(x2b + f);
    }
    __syncthreads();

    // block min/max of x[b,:]
    float mn = 1e30f, mx = -1e30f;
    for (int f = t; f < CDIM; f += 256) {
        float v = xs[f];
        mn = fminf(mn, v); mx = fmaxf(mx, v);
    }
    #pragma unroll
    for (int off = 32; off > 0; off >>= 1) {
        mn = fminf(mn, __shfl_xor(mn, off));
        mx = fmaxf(mx, __shfl_xor(mx, off));
    }
    if (lane == 0) { wred[wv] = mn; wred[4 + wv] = mx; }
    __syncthreads();
    mn = fminf(fminf(wred[0], wred[1]), fminf(wred[2], wred[3]));
    mx = fmaxf(fmaxf(wred[4], wred[5]), fmaxf(wred[6], wred[7]));

    for (int rep = 0; rep < reps; ++rep) {
        for (int r = 0; r < 16; ++r) {
            const int i = rg * 64 + wv * 16 + r;
            const float xi = xs[i];
            const float li = (xi >= 0.f) ? xi * mn : xi * mx; // min_j(x_i*x_j)
            const float nxi = -xi;
            float sum = 0.f, d1 = 0.f, d2 = 0.f;
            #pragma unroll
            for (int g = 0; g < 8; ++g) {
                const int o = g * 256 + lane * 4;
                f32x4 xv = *reinterpret_cast<const f32x4*>(&xs[o]);
                f32x4 v1 = *reinterpret_cast<const f32x4*>(&xs1[o]);
                f32x4 v2 = *reinterpret_cast<const f32x4*>(&xs2[o]);
                #pragma unroll
                for (int c = 0; c < 4; ++c) {
                    float ev = __expf(fmaf(nxi, xv[c], li)); // arg <= ~0
                    sum += ev;
                    d1 = fmaf(ev, v1[c], d1);
                    d2 = fmaf(ev, v2[c], d2);
                }
            }
            #pragma unroll
            for (int off = 32; off > 0; off >>= 1) {
                sum += __shfl_xor(sum, off);
                d1  += __shfl_xor(d1, off);
                d2  += __shfl_xor(d2, off);
            }
            const float inv = 1.f / sum;
            if (lane == 0) {
                out1[b * CDIM + i] = fmaf(d1, inv, xs1[i]);
                out2[b * CDIM + i] = fmaf(d2, inv, xs2[i]);
            }
            float* arow = att + (size_t)(b * CDIM + i) * CDIM;
            #pragma unroll
            for (int g = 0; g < 8; ++g) {
                const int o = g * 256 + lane * 4;
                f32x4 xv = *reinterpret_cast<const f32x4*>(&xs[o]);
                f32x4 v;
                #pragma unroll
                for (int c = 0; c < 4; ++c)
                    v[c] = __expf(fmaf(nxi, xv[c], li)) * inv;
                *reinterpret_cast<f32x4*>(arow + o) = v;
            }
        }
    }
}

extern "C" void kernel_launch(void* const* d_in, const int* in_sizes, int n_in,
                              void* d_out, int out_size, void* d_ws, size_t ws_size,
                              hipStream_t stream) {
    const float* x1   = (const float*)d_in[0];
    const float* x2   = (const float*)d_in[1];
    const float* W    = (const float*)d_in[2];
    const float* bias = (const float*)d_in[3];
    float* out  = (float*)d_out;
    float* out1 = out;
    float* out2 = out + BATCH * CDIM;
    float* att  = out + 2 * BATCH * CDIM;
    float* x    = (float*)d_ws;

    float* partial = out + ((size_t)out_size - (size_t)KT * BATCH * CDIM);

    gemm_partial_k<<<dim3(NT, KT), dim3(256), 0, stream>>>(x1, x2, W, partial);
    reduce_x_k<<<(BATCH * CDIM) / 256, 256, 0, stream>>>(partial, bias, x);
    // reps=4: DIAGNOSTIC ONLY — restores to 1 next round.
    attn_k<<<BATCH * (CDIM / 64), 256, 0, stream>>>(x, x1, x2, out1, out2, att, 4);
}

// Round 7
// 123.040 us; speedup vs baseline: 2.8290x; 2.8290x over previous
//
#include <hip/hip_runtime.h>

#define CDIM 2048
#define BATCH 32
#define K2 4096

typedef float f32x4 __attribute__((ext_vector_type(4)));

// ---- GEMM partial: partial[kt] = xcat[:, k0:k0+BK] @ W[:, k0:k0+BK]^T ----
// Block: BN=64 W-rows x BK=128 k. 256 thr = 8 colgrp x 8 batgrp x 4 k-quarters.
// Thread tile acc[4 batches][8 cols]; b128 LDS reads, XOR-swizzled tiles
// (conflict-free); cross-wave k-quarter reduce via LDS overlay.
#define BN 64
#define BK 128
#define KT (K2 / BK)   // 32
#define NT (CDIM / BN) // 32

__global__ __launch_bounds__(256) void gemm_partial_k(
    const float* __restrict__ x1, const float* __restrict__ x2,
    const float* __restrict__ W, float* __restrict__ partial)
{
    __shared__ float lds[BN * BK + BATCH * BK]; // Wt | Xs, later overlaid by accS
    float* Wt = lds;                 // [64][128], chunk-swizzled
    float* Xs = lds + BN * BK;       // [32][128], chunk-swizzled

    const int nt = blockIdx.x, kt = blockIdx.y;
    const int i0 = nt * BN, k0 = kt * BK;
    const int t = threadIdx.x;
    const int lane = t & 63, ks = t >> 6;   // ks = wave id = k-quarter
    const int cg = lane & 7, bg = lane >> 3;

    const float* xsrc = (k0 < CDIM) ? x1 : x2;
    const int kk0 = k0 & (CDIM - 1);

    // stage W tile: 64x128 f32 = 2048 float4, 8/thread, swizzle chunk^(row>>3)
    #pragma unroll
    for (int r = 0; r < 8; ++r) {
        int f = t + 256 * r;
        int row = f >> 5, kc = f & 31;
        float4 v = *reinterpret_cast<const float4*>(W + (size_t)(i0 + row) * K2 + k0 + kc * 4);
        int sc = kc ^ ((row >> 3) & 7);
        *reinterpret_cast<float4*>(&Wt[row * BK + sc * 4]) = v;
    }
    // stage X tile: 32x128 f32 = 1024 float4, 4/thread, swizzle chunk^(row>>2)
    #pragma unroll
    for (int r = 0; r < 4; ++r) {
        int f = t + 256 * r;
        int row = f >> 5, kc = f & 31;
        float4 v = *reinterpret_cast<const float4*>(xsrc + row * CDIM + kk0 + kc * 4);
        int sc = kc ^ ((row >> 2) & 7);
        *reinterpret_cast<float4*>(&Xs[row * BK + sc * 4]) = v;
    }
    __syncthreads();

    float acc[4][8] = {};
    #pragma unroll 2
    for (int s = 0; s < 8; ++s) {
        const int kc = ks * 8 + s;
        f32x4 xv[4], wv[8];
        #pragma unroll
        for (int bb = 0; bb < 4; ++bb)
            xv[bb] = *reinterpret_cast<const f32x4*>(&Xs[(4 * bg + bb) * BK + (kc ^ bg) * 4]);
        #pragma unroll
        for (int cc = 0; cc < 8; ++cc)
            wv[cc] = *reinterpret_cast<const f32x4*>(&Wt[(8 * cg + cc) * BK + (kc ^ cg) * 4]);
        #pragma unroll
        for (int bb = 0; bb < 4; ++bb)
            #pragma unroll
            for (int cc = 0; cc < 8; ++cc)
                #pragma unroll
                for (int w = 0; w < 4; ++w)
                    acc[bb][cc] = fmaf(xv[bb][w], wv[cc][w], acc[bb][cc]);
    }

    // cross-wave reduce of the 4 k-quarters: accS[4][64][33] overlays lds
    __syncthreads();
    float* accS = lds;
    #pragma unroll
    for (int bb = 0; bb < 4; ++bb)
        #pragma unroll
        for (int cc = 0; cc < 8; ++cc)
            accS[(ks * 64 + lane) * 33 + bb * 8 + cc] = acc[bb][cc];
    __syncthreads();

    {
        const int l0 = t >> 2, q = t & 3;
        float s0[8];
        #pragma unroll
        for (int j = 0; j < 8; ++j) {
            float s = 0.f;
            #pragma unroll
            for (int k = 0; k < 4; ++k)
                s += accS[(k * 64 + l0) * 33 + q * 8 + j];
            s0[j] = s;
        }
        const int b_row = 4 * (l0 >> 3) + q;          // 0..31
        const int icol  = 8 * (l0 & 7);               // 0..56
        float* dst = partial + (size_t)kt * (BATCH * CDIM) + b_row * CDIM + i0 + icol;
        float4 lo = make_float4(s0[0], s0[1], s0[2], s0[3]);
        float4 hi = make_float4(s0[4], s0[5], s0[6], s0[7]);
        *reinterpret_cast<float4*>(dst)     = lo;
        *reinterpret_cast<float4*>(dst + 4) = hi;
    }
}

__global__ __launch_bounds__(256) void reduce_x_k(
    const float* __restrict__ partial, const float* __restrict__ bias,
    float* __restrict__ x)
{
    int idx = blockIdx.x * 256 + threadIdx.x;
    float s = 0.f;
    #pragma unroll
    for (int kt = 0; kt < KT; ++kt) s += partial[(size_t)kt * (BATCH * CDIM) + idx];
    x[idx] = s + bias[idx & (CDIM - 1)];
}

// ---- Attention (R5 structure, reps removed): at measured HBM-write roofline.
__global__ __launch_bounds__(256) void attn_k(
    const float* __restrict__ x, const float* __restrict__ x1,
    const float* __restrict__ x2, float* __restrict__ out1,
    float* __restrict__ out2, float* __restrict__ att)
{
    __shared__ float xs[CDIM];
    __shared__ float xs1[CDIM];
    __shared__ float xs2[CDIM];
    __shared__ float wred[8];
    const int b = blockIdx.x >> 5, rg = blockIdx.x & 31;
    const int t = threadIdx.x;
    const int lane = t & 63, wv = t >> 6;
    const float* xb  = x  + b * CDIM;
    const float* x1b = x1 + b * CDIM;
    const float* x2b = x2 + b * CDIM;

    #pragma unroll
    for (int r = 0; r < 2; ++r) {
        int f = (t + 256 * r) * 4;
        *reinterpret_cast<float4*>(&xs[f])  = *reinterpret_cast<const float4*>(xb  + f);
        *reinterpret_cast<float4*>(&xs1[f]) = *reinterpret_cast<const float4*>(x1b + f);
        *reinterpret_cast<float4*>(&xs2[f]) = *reinterpret_cast<const float4*>(x2b + f);
    }
    __syncthreads();

    float mn = 1e30f, mx = -1e30f;
    for (int f = t; f < CDIM; f += 256) {
        float v = xs[f];
        mn = fminf(mn, v); mx = fmaxf(mx, v);
    }
    #pragma unroll
    for (int off = 32; off > 0; off >>= 1) {
        mn = fminf(mn, __shfl_xor(mn, off));
        mx = fmaxf(mx, __shfl_xor(mx, off));
    }
    if (lane == 0) { wred[wv] = mn; wred[4 + wv] = mx; }
    __syncthreads();
    mn = fminf(fminf(wred[0], wred[1]), fminf(wred[2], wred[3]));
    mx = fmaxf(fmaxf(wred[4], wred[5]), fmaxf(wred[6], wred[7]));

    for (int r = 0; r < 16; ++r) {
        const int i = rg * 64 + wv * 16 + r;
        const float xi = xs[i];
        const float li = (xi >= 0.f) ? xi * mn : xi * mx; // min_j(x_i*x_j), exact
        const float nxi = -xi;
        float sum = 0.f, d1 = 0.f, d2 = 0.f;
        #pragma unroll
        for (int g = 0; g < 8; ++g) {
            const int o = g * 256 + lane * 4;
            f32x4 xv = *reinterpret_cast<const f32x4*>(&xs[o]);
            f32x4 v1 = *reinterpret_cast<const f32x4*>(&xs1[o]);
            f32x4 v2 = *reinterpret_cast<const f32x4*>(&xs2[o]);
            #pragma unroll
            for (int c = 0; c < 4; ++c) {
                float ev = __expf(fmaf(nxi, xv[c], li)); // arg <= ~0
                sum += ev;
                d1 = fmaf(ev, v1[c], d1);
                d2 = fmaf(ev, v2[c], d2);
            }
        }
        #pragma unroll
        for (int off = 32; off > 0; off >>= 1) {
            sum += __shfl_xor(sum, off);
            d1  += __shfl_xor(d1, off);
            d2  += __shfl_xor(d2, off);
        }
        const float inv = 1.f / sum;
        if (lane == 0) {
            out1[b * CDIM + i] = fmaf(d1, inv, xs1[i]);
            out2[b * CDIM + i] = fmaf(d2, inv, xs2[i]);
        }
        float* arow = att + (size_t)(b * CDIM + i) * CDIM;
        #pragma unroll
        for (int g = 0; g < 8; ++g) {
            const int o = g * 256 + lane * 4;
            f32x4 xv = *reinterpret_cast<const f32x4*>(&xs[o]);
            f32x4 v;
            #pragma unroll
            for (int c = 0; c < 4; ++c)
                v[c] = __expf(fmaf(nxi, xv[c], li)) * inv;
            *reinterpret_cast<f32x4*>(arow + o) = v;
        }
    }
}

extern "C" void kernel_launch(void* const* d_in, const int* in_sizes, int n_in,
                              void* d_out, int out_size, void* d_ws, size_t ws_size,
                              hipStream_t stream) {
    const float* x1   = (const float*)d_in[0];
    const float* x2   = (const float*)d_in[1];
    const float* W    = (const float*)d_in[2];
    const float* bias = (const float*)d_in[3];
    float* out  = (float*)d_out;
    float* out1 = out;
    float* out2 = out + BATCH * CDIM;
    float* att  = out + 2 * BATCH * CDIM;
    float* x    = (float*)d_ws;

    // GEMM partials live in the tail of the attention region; fully consumed
    // by reduce_x_k before attn_k overwrites that region.
    float* partial = out + ((size_t)out_size - (size_t)KT * BATCH * CDIM);

    gemm_partial_k<<<dim3(NT, KT), dim3(256), 0, stream>>>(x1, x2, W, partial);
    reduce_x_k<<<(BATCH * CDIM) / 256, 256, 0, stream>>>(partial, bias, x);
    attn_k<<<BATCH * (CDIM / 64), 256, 0, stream>>>(x, x1, x2, out1, out2, att);
}